// Round 4
// baseline (2153.380 us; speedup 1.0000x reference)
//
#include <hip/hip_runtime.h>

#define TT 2048
#define HH 64
#define II 6
#define OO 6
#define GG 256
#define NTHR 512   // 8 waves = 2/SIMD, 1 block/CU, VGPR budget 256

__device__ __forceinline__ float fast_sig(float v) {
    return __builtin_amdgcn_rcpf(1.0f + __expf(-v));
}
__device__ __forceinline__ float fast_tanh(float v) {
    // tanh(v) = 1 - 2/(exp(2v)+1); graceful at +-inf
    return 1.0f - 2.0f * __builtin_amdgcn_rcpf(__expf(2.0f * v) + 1.0f);
}

__global__
__attribute__((amdgpu_flat_work_group_size(NTHR, NTHR)))
__attribute__((amdgpu_waves_per_eu(2, 2)))   // pin exactly 2 waves/SIMD -> 256 VGPR budget
void lstm_fused_kernel(const float* __restrict__ x,
                       const float* __restrict__ Wih0, const float* __restrict__ Whh0,
                       const float* __restrict__ b0,
                       const float* __restrict__ Wih1, const float* __restrict__ Whh1,
                       const float* __restrict__ b1,
                       const float* __restrict__ W1, const float* __restrict__ bf1,
                       const float* __restrict__ W2, const float* __restrict__ bf2,
                       float* __restrict__ out)
{
    const int row = blockIdx.x;        // batch row
    const int tid = threadIdx.x;
    const bool isA = tid < GG;         // A: layer0 gate + xg1 ; B: layer1 gate + FC
    const int j = tid & (GG - 1);

    __shared__ __attribute__((aligned(16))) float h0buf[2][HH];
    __shared__ __attribute__((aligned(16))) float h1buf[2][HH];
    __shared__ __attribute__((aligned(16))) float rbuf[2][HH];
    __shared__ __attribute__((aligned(16))) float xgbuf[2][GG];
    __shared__ __attribute__((aligned(16))) float gA[GG];
    __shared__ __attribute__((aligned(16))) float gB[GG];

    if (tid < HH) {
        h0buf[0][tid] = 0.f; h0buf[1][tid] = 0.f;
        h1buf[0][tid] = 0.f; h1buf[1][tid] = 0.f;
    }

    // two weight rows per thread:
    //   A: wG = Whh0[j]   (gate0, dots h0[t-1]),  wF = Wih1[j] (xg1, dots h0[t-1])
    //   B: wG = Whh1[j]   (gate1, dots h1[t-3]),  wF = W1[j] (j<64, dots h1[t-3])
    //                                         or   W2[j-64] (j in [64,70), dots rbuf[t-4])
    const float* pG; const float* pF;
    float biasG = 0.f, biasF = 0.f;
    if (isA) {
        pG = Whh0 + j * HH; biasG = b0[j];
        pF = Wih1 + j * HH; biasF = b1[j];
    } else {
        pG = Whh1 + j * HH;
        if (j < HH)           { pF = W1 + j * HH;        biasF = bf1[j]; }
        else if (j < HH + OO) { pF = W2 + (j - HH) * HH; biasF = bf2[j - HH]; }
        else                  { pF = W1; }               // dummy row, result unused
    }

    float4 wG[16], wF[16];
    #pragma unroll
    for (int q = 0; q < 16; ++q) {
        wG[q] = reinterpret_cast<const float4*>(pG)[q];
        wF[q] = reinterpret_cast<const float4*>(pF)[q];
    }
    // opaque: keep weights resident, forbid remat as loads inside the loop
    #pragma unroll
    for (int q = 0; q < 16; ++q) {
        asm volatile("" : "+v"(wG[q].x), "+v"(wG[q].y), "+v"(wG[q].z), "+v"(wG[q].w));
        asm volatile("" : "+v"(wF[q].x), "+v"(wF[q].y), "+v"(wF[q].z), "+v"(wF[q].w));
    }

    // A-threads: cached Wih0 row + current x[t]
    float wx0=0.f,wx1=0.f,wx2=0.f,wx3=0.f,wx4=0.f,wx5=0.f;
    float xc0=0.f,xc1=0.f,xc2=0.f,xc3=0.f,xc4=0.f,xc5=0.f;
    const float* xrow = x + (size_t)row * TT * II;
    if (isA) {
        wx0 = Wih0[j*II+0]; wx1 = Wih0[j*II+1]; wx2 = Wih0[j*II+2];
        wx3 = Wih0[j*II+3]; wx4 = Wih0[j*II+4]; wx5 = Wih0[j*II+5];
        xc0 = xrow[0]; xc1 = xrow[1]; xc2 = xrow[2];
        xc3 = xrow[3]; xc4 = xrow[4]; xc5 = xrow[5];
    }

    float* outrow = out + (size_t)row * TT * OO;
    float c = 0.f;   // cell state (phase-2 threads: tid 0-63 layer0, 64-127 layer1)

    __syncthreads();

    for (int t = 0; t <= TT + 3; ++t) {
        // ---------------- phase 1 : all dot products ----------------
        if (isA) {
            // gate0 at step t (needs h0[t-1]) and xg1[t-1] (needs h0[t-1]) — one read
            const float4* hp = reinterpret_cast<const float4*>(h0buf[(t - 1) & 1]);
            float accG = biasG + wx0*xc0 + wx1*xc1 + wx2*xc2
                               + wx3*xc3 + wx4*xc4 + wx5*xc5;
            float accF = biasF;
            #pragma unroll
            for (int q = 0; q < 16; ++q) {
                float4 hv = hp[q];
                accG += wG[q].x*hv.x + wG[q].y*hv.y + wG[q].z*hv.z + wG[q].w*hv.w;
                accF += wF[q].x*hv.x + wF[q].y*hv.y + wF[q].z*hv.z + wF[q].w*hv.w;
            }
            if (t < TT)
                gA[j] = (j < 128 || j >= 192) ? fast_sig(accG) : fast_tanh(accG);
            if (t >= 1 && t <= TT)
                xgbuf[(t - 1) & 1][j] = accF;
            if (t + 1 < TT) {   // prefetch next x (uniform across block -> scalar loads)
                const float* xn = xrow + (size_t)(t + 1) * II;
                xc0 = xn[0]; xc1 = xn[1]; xc2 = xn[2];
                xc3 = xn[3]; xc4 = xn[4]; xc5 = xn[5];
            }
        } else {
            // gate1 at s2=t-2 (needs h1[t-3]), FC1 at s3=t-3 (needs h1[t-3]),
            // FC2 at s4=t-4 (needs rbuf[t-4])
            const int s2 = t - 2, s3 = t - 3, s4 = t - 4;
            const float4* hpG = reinterpret_cast<const float4*>(h1buf[(t - 3) & 1]);
            const float4* hpF = (j >= HH && j < HH + OO)
                ? reinterpret_cast<const float4*>(rbuf[(t - 4) & 1]) : hpG;
            float accG = xgbuf[s2 & 1][j];   // b1 already folded in by A-threads
            float accF = biasF;
            #pragma unroll
            for (int q = 0; q < 16; ++q) {
                float4 hg = hpG[q];
                float4 hf = hpF[q];
                accG += wG[q].x*hg.x + wG[q].y*hg.y + wG[q].z*hg.z + wG[q].w*hg.w;
                accF += wF[q].x*hf.x + wF[q].y*hf.y + wF[q].z*hf.z + wF[q].w*hf.w;
            }
            if (s2 >= 0 && s2 < TT)
                gB[j] = (j < 128 || j >= 192) ? fast_sig(accG) : fast_tanh(accG);
            if (j < HH && s3 >= 0 && s3 < TT)
                rbuf[s3 & 1][j] = fmaxf(accF, 0.f);
            if (j >= HH && j < HH + OO && s4 >= 0 && s4 < TT)
                outrow[(size_t)s4 * OO + (j - HH)] = accF;
        }
        __syncthreads();
        // ---------------- phase 2 : cell updates ----------------
        if (tid < 64) {
            if (t < TT) {
                float ig = gA[tid], fg = gA[64+tid], gg = gA[128+tid], og = gA[192+tid];
                c = fg * c + ig * gg;
                h0buf[t & 1][tid] = og * fast_tanh(c);
            }
        } else if (tid < 128) {
            const int s = t - 2;
            if (s >= 0 && s < TT) {
                const int k = tid - 64;
                float ig = gB[k], fg = gB[64+k], gg = gB[128+k], og = gB[192+k];
                c = fg * c + ig * gg;
                h1buf[s & 1][k] = og * fast_tanh(c);
            }
        }
        __syncthreads();
    }
}

extern "C" void kernel_launch(void* const* d_in, const int* in_sizes, int n_in,
                              void* d_out, int out_size, void* d_ws, size_t ws_size,
                              hipStream_t stream) {
    const float* xp   = (const float*)d_in[0];
    const float* Wih0 = (const float*)d_in[1];
    const float* Whh0 = (const float*)d_in[2];
    const float* b0   = (const float*)d_in[3];
    const float* Wih1 = (const float*)d_in[4];
    const float* Whh1 = (const float*)d_in[5];
    const float* b1   = (const float*)d_in[6];
    const float* W1   = (const float*)d_in[7];
    const float* bf1  = (const float*)d_in[8];
    const float* W2   = (const float*)d_in[9];
    const float* bf2  = (const float*)d_in[10];
    float* out = (float*)d_out;

    lstm_fused_kernel<<<dim3(256), dim3(NTHR), 0, stream>>>(
        xp, Wih0, Whh0, b0, Wih1, Whh1, b1, W1, bf1, W2, bf2, out);
}

// Round 6
// 1905.370 us; speedup vs baseline: 1.1302x; 1.1302x over previous
//
#include <hip/hip_runtime.h>

#define TT 2048
#define HH 64
#define II 6
#define OO 6
#define NTHR 512   // 8 waves = 2/SIMD pinned -> 256 VGPR budget

typedef float f32x4 __attribute__((ext_vector_type(4)));

__device__ __forceinline__ float fast_sig(float v) {
    return __builtin_amdgcn_rcpf(1.0f + __expf(-v));
}
__device__ __forceinline__ float fast_tanh(float v) {
    // tanh(v) = 1 - 2/(exp(2v)+1); graceful at +-inf
    return 1.0f - 2.0f * __builtin_amdgcn_rcpf(__expf(2.0f * v) + 1.0f);
}

__global__
__attribute__((amdgpu_flat_work_group_size(NTHR, NTHR)))
__attribute__((amdgpu_waves_per_eu(2, 2)))
void lstm_fused_kernel(const float* __restrict__ x,
                       const float* __restrict__ Wih0, const float* __restrict__ Whh0,
                       const float* __restrict__ b0,
                       const float* __restrict__ Wih1, const float* __restrict__ Whh1,
                       const float* __restrict__ b1,
                       const float* __restrict__ W1, const float* __restrict__ bf1,
                       const float* __restrict__ W2, const float* __restrict__ bf2,
                       float* __restrict__ out)
{
    const int row = blockIdx.x;        // batch row
    const int tid = threadIdx.x;
    const bool isA = tid < 256;        // A: layer0 gates + Wih1 row ; B: layer1 gates + FC
    const int fj = tid & 255;          // row-local index
    const int k  = fj >> 2;            // hidden unit
    const int g  = fj & 3;             // gate (0=i,1=f,2=g,3=o), lanes 4k..4k+3 same wave
    const int j  = g * HH + k;         // row in the 4H-stacked weight matrices

    __shared__ __attribute__((aligned(16))) float h0buf[2][HH];
    __shared__ __attribute__((aligned(16))) float h1buf[2][HH];
    __shared__ __attribute__((aligned(16))) float rbuf[2][HH];
    __shared__ __attribute__((aligned(16))) float xgbuf[2][256];

    if (tid < HH) {
        h0buf[0][tid] = 0.f; h0buf[1][tid] = 0.f;
        h1buf[0][tid] = 0.f; h1buf[1][tid] = 0.f;
        rbuf[0][tid]  = 0.f; rbuf[1][tid]  = 0.f;
    }

    // weight rows: A: wG=Whh0[j], wF=Wih1[j].  B: wG=Whh1[j], wF=W1[fj]/W2[fj-64]/dummy
    const float* pG;
    const float* pF;
    float biasG = 0.f, biasF = 0.f;
    if (isA) {
        pG = Whh0 + j * HH; biasG = b0[j];
        pF = Wih1 + j * HH; biasF = b1[j];
    } else {
        pG = Whh1 + j * HH;           // b1 folded in by A via xgbuf
        if (fj < HH)           { pF = W1 + fj * HH;        biasF = bf1[fj]; }
        else if (fj < HH + OO) { pF = W2 + (fj - HH) * HH; biasF = bf2[fj - HH]; }
        else                   { pF = W1; }                // dummy, result unused
    }

    f32x4 wG[16], wF[16];
    #pragma unroll
    for (int q = 0; q < 16; ++q) {
        wG[q] = reinterpret_cast<const f32x4*>(pG)[q];
        wF[q] = reinterpret_cast<const f32x4*>(pF)[q];
    }
    // whole-vector opaque ties: asm outputs cannot be rematerialized as loads
    asm volatile("" : "+v"(wG[0]), "+v"(wG[1]), "+v"(wG[2]),  "+v"(wG[3]),
                      "+v"(wG[4]), "+v"(wG[5]), "+v"(wG[6]),  "+v"(wG[7]),
                      "+v"(wG[8]), "+v"(wG[9]), "+v"(wG[10]), "+v"(wG[11]),
                      "+v"(wG[12]),"+v"(wG[13]),"+v"(wG[14]), "+v"(wG[15]));
    asm volatile("" : "+v"(wF[0]), "+v"(wF[1]), "+v"(wF[2]),  "+v"(wF[3]),
                      "+v"(wF[4]), "+v"(wF[5]), "+v"(wF[6]),  "+v"(wF[7]),
                      "+v"(wF[8]), "+v"(wF[9]), "+v"(wF[10]), "+v"(wF[11]),
                      "+v"(wF[12]),"+v"(wF[13]),"+v"(wF[14]), "+v"(wF[15]));

    // A: cached Wih0 row + current x[t]
    float wx0=0.f,wx1=0.f,wx2=0.f,wx3=0.f,wx4=0.f,wx5=0.f;
    float xc0=0.f,xc1=0.f,xc2=0.f,xc3=0.f,xc4=0.f,xc5=0.f;
    const float* xrow = x + (size_t)row * TT * II;
    if (isA) {
        wx0 = Wih0[j*II+0]; wx1 = Wih0[j*II+1]; wx2 = Wih0[j*II+2];
        wx3 = Wih0[j*II+3]; wx4 = Wih0[j*II+4]; wx5 = Wih0[j*II+5];
        xc0 = xrow[0]; xc1 = xrow[1]; xc2 = xrow[2];
        xc3 = xrow[3]; xc4 = xrow[4]; xc5 = xrow[5];
    }

    float* outrow = out + (size_t)row * TT * OO;
    float c = 0.f;   // cell state, replicated across the 4 lanes of each unit group

    __syncthreads();

    // slot parities: (t-1)&1 == (t-3)&1 == (t+1)&1 ; (t-2)&1 == (t-4)&1 == t&1
    for (int t = 0; t <= TT + 3; ++t) {
        const int sl_prev = (t + 1) & 1;   // h0[t-1], h1[t-3], rbuf write slot (s3)
        const int sl_cur  = t & 1;         // h0[t], h1[t-2], xgbuf read (s2), rbuf read (s4)

        if (isA) {
            // both dots read h0[t-1]
            const f32x4* hp = reinterpret_cast<const f32x4*>(h0buf[sl_prev]);
            f32x4 accG = {biasG + wx0*xc0 + wx1*xc1 + wx2*xc2,
                          wx3*xc3 + wx4*xc4 + wx5*xc5, 0.f, 0.f};
            f32x4 accF = {biasF, 0.f, 0.f, 0.f};
            #pragma unroll
            for (int q = 0; q < 16; ++q) {
                f32x4 hv = hp[q];
                accG += wG[q] * hv;     // -> v_pk_fma_f32
                accF += wF[q] * hv;
            }
            if (t <= TT) xgbuf[sl_prev][fj] = (accF[0]+accF[1])+(accF[2]+accF[3]);
            if (t < TT) {
                float acc = (accG[0]+accG[1])+(accG[2]+accG[3]);
                float a = (g == 2) ? fast_tanh(acc) : fast_sig(acc);
                // 4-lane butterfly: lane g obtains a_{g^1}, a_{g^2}, a_{g^3}
                float p  = __shfl_xor(a, 1);
                float q2 = __shfl_xor(a, 2);
                float r2 = __shfl_xor(p, 2);
                float A0 = (g & 1) ? p  : a;    // even member of own pair
                float A1 = (g & 1) ? a  : p;    // odd member of own pair
                float B0 = (g & 1) ? r2 : q2;   // even member of other pair
                float B1 = (g & 1) ? q2 : r2;   // odd member of other pair
                float i_ = (g & 2) ? B0 : A0;
                float f_ = (g & 2) ? B1 : A1;
                float gg = (g & 2) ? A0 : B0;
                float o_ = (g & 2) ? A1 : B1;
                c = f_ * c + i_ * gg;
                float h = o_ * fast_tanh(c);
                if (g == 0) h0buf[sl_cur][k] = h;
                if (t + 1 < TT) {   // prefetch next x
                    const float* xn = xrow + (size_t)(t + 1) * II;
                    xc0 = xn[0]; xc1 = xn[1]; xc2 = xn[2];
                    xc3 = xn[3]; xc4 = xn[4]; xc5 = xn[5];
                }
            }
        } else {
            const int s2 = t - 2, s3 = t - 3, s4 = t - 4;
            // gates1 + FC1 read h1[t-3]; FC2 lanes read rbuf[t-4] (wave-uniform split)
            const f32x4* hpG = reinterpret_cast<const f32x4*>(h1buf[sl_prev]);
            const f32x4* hpF = (fj < HH)
                ? hpG : reinterpret_cast<const f32x4*>(rbuf[sl_cur]);
            f32x4 accG = {xgbuf[sl_cur][fj], 0.f, 0.f, 0.f};   // b1 + Wih1.h0[s2] from A
            f32x4 accF = {biasF, 0.f, 0.f, 0.f};
            #pragma unroll
            for (int q = 0; q < 16; ++q) {
                f32x4 hg = hpG[q];
                f32x4 hf = hpF[q];
                accG += wG[q] * hg;
                accF += wF[q] * hf;
            }
            if (s2 >= 0 && s2 < TT) {
                float acc = (accG[0]+accG[1])+(accG[2]+accG[3]);
                float a = (g == 2) ? fast_tanh(acc) : fast_sig(acc);
                float p  = __shfl_xor(a, 1);
                float q2 = __shfl_xor(a, 2);
                float r2 = __shfl_xor(p, 2);
                float A0 = (g & 1) ? p  : a;
                float A1 = (g & 1) ? a  : p;
                float B0 = (g & 1) ? r2 : q2;
                float B1 = (g & 1) ? q2 : r2;
                float i_ = (g & 2) ? B0 : A0;
                float f_ = (g & 2) ? B1 : A1;
                float gg = (g & 2) ? A0 : B0;
                float o_ = (g & 2) ? A1 : B1;
                c = f_ * c + i_ * gg;
                float h = o_ * fast_tanh(c);
                if (g == 0) h1buf[sl_cur][k] = h;
            }
            float fc = (accF[0]+accF[1])+(accF[2]+accF[3]);
            if (fj < HH) {
                if (s3 >= 0 && s3 < TT) rbuf[sl_prev][fj] = fmaxf(fc, 0.f);
            } else if (fj < HH + OO) {
                if (s4 >= 0 && s4 < TT) outrow[(size_t)s4 * OO + (fj - HH)] = fc;
            }
        }
        // loop-carried register pin: weights must live in VGPRs at every iter boundary
        asm volatile("" : "+v"(wG[0]), "+v"(wG[1]), "+v"(wG[2]),  "+v"(wG[3]),
                          "+v"(wG[4]), "+v"(wG[5]), "+v"(wG[6]),  "+v"(wG[7]),
                          "+v"(wG[8]), "+v"(wG[9]), "+v"(wG[10]), "+v"(wG[11]),
                          "+v"(wG[12]),"+v"(wG[13]),"+v"(wG[14]), "+v"(wG[15]));
        asm volatile("" : "+v"(wF[0]), "+v"(wF[1]), "+v"(wF[2]),  "+v"(wF[3]),
                          "+v"(wF[4]), "+v"(wF[5]), "+v"(wF[6]),  "+v"(wF[7]),
                          "+v"(wF[8]), "+v"(wF[9]), "+v"(wF[10]), "+v"(wF[11]),
                          "+v"(wF[12]),"+v"(wF[13]),"+v"(wF[14]), "+v"(wF[15]));
        __syncthreads();   // single barrier publishes all slot writes for iter t+1
    }
}

extern "C" void kernel_launch(void* const* d_in, const int* in_sizes, int n_in,
                              void* d_out, int out_size, void* d_ws, size_t ws_size,
                              hipStream_t stream) {
    const float* xp   = (const float*)d_in[0];
    const float* Wih0 = (const float*)d_in[1];
    const float* Whh0 = (const float*)d_in[2];
    const float* b0   = (const float*)d_in[3];
    const float* Wih1 = (const float*)d_in[4];
    const float* Whh1 = (const float*)d_in[5];
    const float* b1   = (const float*)d_in[6];
    const float* W1   = (const float*)d_in[7];
    const float* bf1  = (const float*)d_in[8];
    const float* W2   = (const float*)d_in[9];
    const float* bf2  = (const float*)d_in[10];
    float* out = (float*)d_out;

    lstm_fused_kernel<<<dim3(256), dim3(NTHR), 0, stream>>>(
        xp, Wih0, Whh0, b0, Wih1, Whh1, b1, W1, bf1, W2, bf2, out);
}

// Round 7
// 1495.928 us; speedup vs baseline: 1.4395x; 1.2737x over previous
//
#include <hip/hip_runtime.h>

#define TT 2048
#define HH 64
#define II 6
#define OO 6
#define NTHR 512   // 8 waves = 2/SIMD pinned

typedef float  f32x4 __attribute__((ext_vector_type(4)));
typedef _Float16 f16x2 __attribute__((ext_vector_type(2)));
typedef _Float16 f16x8 __attribute__((ext_vector_type(8)));

__device__ __forceinline__ float fast_sig(float v) {
    return __builtin_amdgcn_rcpf(1.0f + __expf(-v));
}
__device__ __forceinline__ float fast_tanh(float v) {
    return 1.0f - 2.0f * __builtin_amdgcn_rcpf(__expf(2.0f * v) + 1.0f);
}

__global__
__attribute__((amdgpu_flat_work_group_size(NTHR, NTHR)))
__attribute__((amdgpu_waves_per_eu(2, 2)))
void lstm_fused_kernel(const float* __restrict__ x,
                       const float* __restrict__ Wih0, const float* __restrict__ Whh0,
                       const float* __restrict__ b0,
                       const float* __restrict__ Wih1, const float* __restrict__ Whh1,
                       const float* __restrict__ b1,
                       const float* __restrict__ W1, const float* __restrict__ bf1,
                       const float* __restrict__ W2, const float* __restrict__ bf2,
                       float* __restrict__ out)
{
    const int row = blockIdx.x;        // batch row
    const int tid = threadIdx.x;
    const bool isA = tid < 256;        // A: layer0 gates + Wih1 row ; B: layer1 gates + FC
    const int fj = tid & 255;
    const int k  = fj >> 2;            // hidden unit
    const int g  = fj & 3;             // gate (0=i,1=f,2=g,3=o), lanes 4k..4k+3 same wave
    const int j  = g * HH + k;         // row in 4H-stacked weight matrices

    // f16 hidden-state / relu buffers (matvec inputs); f32 for xg1 handoff
    __shared__ __attribute__((aligned(16))) _Float16 h0f16[2][HH];
    __shared__ __attribute__((aligned(16))) _Float16 h1f16[2][HH];
    __shared__ __attribute__((aligned(16))) _Float16 rb16[2][HH];
    __shared__ __attribute__((aligned(16))) float    xgbuf[2][256];

    if (tid < HH) {
        h0f16[0][tid] = (_Float16)0.f; h0f16[1][tid] = (_Float16)0.f;
        h1f16[0][tid] = (_Float16)0.f; h1f16[1][tid] = (_Float16)0.f;
        rb16[0][tid]  = (_Float16)0.f; rb16[1][tid]  = (_Float16)0.f;
    }

    // weight rows: A: wG=Whh0[j], wF=Wih1[j].  B: wG=Whh1[j], wF=W1[fj]/W2[fj-64]/dummy
    const float* pG;
    const float* pF;
    float biasG = 0.f, biasF = 0.f;
    if (isA) {
        pG = Whh0 + j * HH; biasG = b0[j];
        pF = Wih1 + j * HH; biasF = b1[j];
    } else {
        pG = Whh1 + j * HH;           // b1 folded in by A via xgbuf
        if (fj < HH)           { pF = W1 + fj * HH;        biasF = bf1[fj]; }
        else if (fj < HH + OO) { pF = W2 + (fj - HH) * HH; biasF = bf2[fj - HH]; }
        else                   { pF = W1; }                // dummy, result unused
    }

    // load f32 rows, convert once to packed f16 pairs: 32 VGPRs per row
    f16x2 wG[32], wF[32];
    #pragma unroll
    for (int q = 0; q < 16; ++q) {
        f32x4 vg = reinterpret_cast<const f32x4*>(pG)[q];
        f32x4 vf = reinterpret_cast<const f32x4*>(pF)[q];
        wG[2*q]   = f16x2{(_Float16)vg[0], (_Float16)vg[1]};
        wG[2*q+1] = f16x2{(_Float16)vg[2], (_Float16)vg[3]};
        wF[2*q]   = f16x2{(_Float16)vf[0], (_Float16)vf[1]};
        wF[2*q+1] = f16x2{(_Float16)vf[2], (_Float16)vf[3]};
    }
    // opaque ties (once): asm outputs can't be rematerialized as loads
    asm volatile("" : "+v"(wG[0]), "+v"(wG[1]), "+v"(wG[2]),  "+v"(wG[3]),
                      "+v"(wG[4]), "+v"(wG[5]), "+v"(wG[6]),  "+v"(wG[7]),
                      "+v"(wG[8]), "+v"(wG[9]), "+v"(wG[10]), "+v"(wG[11]),
                      "+v"(wG[12]),"+v"(wG[13]),"+v"(wG[14]), "+v"(wG[15]));
    asm volatile("" : "+v"(wG[16]),"+v"(wG[17]),"+v"(wG[18]), "+v"(wG[19]),
                      "+v"(wG[20]),"+v"(wG[21]),"+v"(wG[22]), "+v"(wG[23]),
                      "+v"(wG[24]),"+v"(wG[25]),"+v"(wG[26]), "+v"(wG[27]),
                      "+v"(wG[28]),"+v"(wG[29]),"+v"(wG[30]), "+v"(wG[31]));
    asm volatile("" : "+v"(wF[0]), "+v"(wF[1]), "+v"(wF[2]),  "+v"(wF[3]),
                      "+v"(wF[4]), "+v"(wF[5]), "+v"(wF[6]),  "+v"(wF[7]),
                      "+v"(wF[8]), "+v"(wF[9]), "+v"(wF[10]), "+v"(wF[11]),
                      "+v"(wF[12]),"+v"(wF[13]),"+v"(wF[14]), "+v"(wF[15]));
    asm volatile("" : "+v"(wF[16]),"+v"(wF[17]),"+v"(wF[18]), "+v"(wF[19]),
                      "+v"(wF[20]),"+v"(wF[21]),"+v"(wF[22]), "+v"(wF[23]),
                      "+v"(wF[24]),"+v"(wF[25]),"+v"(wF[26]), "+v"(wF[27]),
                      "+v"(wF[28]),"+v"(wF[29]),"+v"(wF[30]), "+v"(wF[31]));

    // A: f32 Wih0 row + current x[t] (x part stays full f32)
    float wx0=0.f,wx1=0.f,wx2=0.f,wx3=0.f,wx4=0.f,wx5=0.f;
    float xc0=0.f,xc1=0.f,xc2=0.f,xc3=0.f,xc4=0.f,xc5=0.f;
    const float* xrow = x + (size_t)row * TT * II;
    if (isA) {
        wx0 = Wih0[j*II+0]; wx1 = Wih0[j*II+1]; wx2 = Wih0[j*II+2];
        wx3 = Wih0[j*II+3]; wx4 = Wih0[j*II+4]; wx5 = Wih0[j*II+5];
        xc0 = xrow[0]; xc1 = xrow[1]; xc2 = xrow[2];
        xc3 = xrow[3]; xc4 = xrow[4]; xc5 = xrow[5];
    }

    float* outrow = out + (size_t)row * TT * OO;
    float c = 0.f;   // cell state, replicated across the 4 lanes of each unit group

    __syncthreads();

    // slot parities (verified in R6): sl_prev=(t+1)&1 for {h0[t-1],h1[t-3],rbuf s3 write};
    // sl_cur=t&1 for {h0[t] write, h1[t-2] write, xgbuf s2 read, rbuf s4 read}
    for (int t = 0; t <= TT + 3; ++t) {
        const int sl_prev = (t + 1) & 1;
        const int sl_cur  = t & 1;

        if (isA) {
            const f16x8* hp = reinterpret_cast<const f16x8*>(h0f16[sl_prev]);
            float accG = biasG + wx0*xc0 + wx1*xc1 + wx2*xc2
                               + wx3*xc3 + wx4*xc4 + wx5*xc5;
            float accF = biasF;
            #pragma unroll
            for (int q = 0; q < 8; ++q) {
                f16x8 hv = hp[q];
                f16x2 p0 = __builtin_shufflevector(hv, hv, 0, 1);
                f16x2 p1 = __builtin_shufflevector(hv, hv, 2, 3);
                f16x2 p2 = __builtin_shufflevector(hv, hv, 4, 5);
                f16x2 p3 = __builtin_shufflevector(hv, hv, 6, 7);
                accG = __builtin_amdgcn_fdot2(wG[4*q+0], p0, accG, false);
                accG = __builtin_amdgcn_fdot2(wG[4*q+1], p1, accG, false);
                accG = __builtin_amdgcn_fdot2(wG[4*q+2], p2, accG, false);
                accG = __builtin_amdgcn_fdot2(wG[4*q+3], p3, accG, false);
                accF = __builtin_amdgcn_fdot2(wF[4*q+0], p0, accF, false);
                accF = __builtin_amdgcn_fdot2(wF[4*q+1], p1, accF, false);
                accF = __builtin_amdgcn_fdot2(wF[4*q+2], p2, accF, false);
                accF = __builtin_amdgcn_fdot2(wF[4*q+3], p3, accF, false);
            }
            if (t <= TT) xgbuf[sl_prev][fj] = accF;        // xg1[t-1], f32
            if (t < TT) {
                float a = (g == 2) ? fast_tanh(accG) : fast_sig(accG);
                float p  = __shfl_xor(a, 1);
                float q2 = __shfl_xor(a, 2);
                float r2 = __shfl_xor(p, 2);
                float A0 = (g & 1) ? p  : a;
                float A1 = (g & 1) ? a  : p;
                float B0 = (g & 1) ? r2 : q2;
                float B1 = (g & 1) ? q2 : r2;
                float i_ = (g & 2) ? B0 : A0;
                float f_ = (g & 2) ? B1 : A1;
                float gg = (g & 2) ? A0 : B0;
                float o_ = (g & 2) ? A1 : B1;
                c = f_ * c + i_ * gg;
                float h = o_ * fast_tanh(c);
                if (g == 0) h0f16[sl_cur][k] = (_Float16)h;
                if (t + 1 < TT) {
                    const float* xn = xrow + (size_t)(t + 1) * II;
                    xc0 = xn[0]; xc1 = xn[1]; xc2 = xn[2];
                    xc3 = xn[3]; xc4 = xn[4]; xc5 = xn[5];
                }
            }
        } else {
            const int s2 = t - 2, s3 = t - 3, s4 = t - 4;
            // wave-uniform F-operand: wave fj<64 -> h1 (==G operand), fj 64..127 -> rbuf,
            // fj>=128 -> dummy (h1)
            const f16x8* hpG = reinterpret_cast<const f16x8*>(h1f16[sl_prev]);
            const f16x8* hpF = ((fj >> 6) == 1)
                ? reinterpret_cast<const f16x8*>(rb16[sl_cur]) : hpG;
            float accG = xgbuf[sl_cur][fj];   // b1 + Wih1.h0[s2] from A (f32)
            float accF = biasF;
            #pragma unroll
            for (int q = 0; q < 8; ++q) {
                f16x8 hg = hpG[q];
                f16x8 hf = hpF[q];
                f16x2 g0 = __builtin_shufflevector(hg, hg, 0, 1);
                f16x2 g1 = __builtin_shufflevector(hg, hg, 2, 3);
                f16x2 g2 = __builtin_shufflevector(hg, hg, 4, 5);
                f16x2 g3 = __builtin_shufflevector(hg, hg, 6, 7);
                f16x2 f0 = __builtin_shufflevector(hf, hf, 0, 1);
                f16x2 f1 = __builtin_shufflevector(hf, hf, 2, 3);
                f16x2 f2 = __builtin_shufflevector(hf, hf, 4, 5);
                f16x2 f3 = __builtin_shufflevector(hf, hf, 6, 7);
                accG = __builtin_amdgcn_fdot2(wG[4*q+0], g0, accG, false);
                accG = __builtin_amdgcn_fdot2(wG[4*q+1], g1, accG, false);
                accG = __builtin_amdgcn_fdot2(wG[4*q+2], g2, accG, false);
                accG = __builtin_amdgcn_fdot2(wG[4*q+3], g3, accG, false);
                accF = __builtin_amdgcn_fdot2(wF[4*q+0], f0, accF, false);
                accF = __builtin_amdgcn_fdot2(wF[4*q+1], f1, accF, false);
                accF = __builtin_amdgcn_fdot2(wF[4*q+2], f2, accF, false);
                accF = __builtin_amdgcn_fdot2(wF[4*q+3], f3, accF, false);
            }
            if (s2 >= 0 && s2 < TT) {
                float a = (g == 2) ? fast_tanh(accG) : fast_sig(accG);
                float p  = __shfl_xor(a, 1);
                float q2 = __shfl_xor(a, 2);
                float r2 = __shfl_xor(p, 2);
                float A0 = (g & 1) ? p  : a;
                float A1 = (g & 1) ? a  : p;
                float B0 = (g & 1) ? r2 : q2;
                float B1 = (g & 1) ? q2 : r2;
                float i_ = (g & 2) ? B0 : A0;
                float f_ = (g & 2) ? B1 : A1;
                float gg = (g & 2) ? A0 : B0;
                float o_ = (g & 2) ? A1 : B1;
                c = f_ * c + i_ * gg;
                float h = o_ * fast_tanh(c);
                if (g == 0) h1f16[sl_cur][k] = (_Float16)h;
            }
            if (fj < HH) {
                if (s3 >= 0 && s3 < TT) rb16[sl_prev][fj] = (_Float16)fmaxf(accF, 0.f);
            } else if (fj < HH + OO) {
                if (s4 >= 0 && s4 < TT) outrow[(size_t)s4 * OO + (fj - HH)] = accF;
            }
        }
        __syncthreads();   // single barrier publishes all slot writes for iter t+1
    }
}

extern "C" void kernel_launch(void* const* d_in, const int* in_sizes, int n_in,
                              void* d_out, int out_size, void* d_ws, size_t ws_size,
                              hipStream_t stream) {
    const float* xp   = (const float*)d_in[0];
    const float* Wih0 = (const float*)d_in[1];
    const float* Whh0 = (const float*)d_in[2];
    const float* b0   = (const float*)d_in[3];
    const float* Wih1 = (const float*)d_in[4];
    const float* Whh1 = (const float*)d_in[5];
    const float* b1   = (const float*)d_in[6];
    const float* W1   = (const float*)d_in[7];
    const float* bf1  = (const float*)d_in[8];
    const float* W2   = (const float*)d_in[9];
    const float* bf2  = (const float*)d_in[10];
    float* out = (float*)d_out;

    lstm_fused_kernel<<<dim3(256), dim3(NTHR), 0, stream>>>(
        xp, Wih0, Whh0, b0, Wih1, Whh1, b1, W1, bf1, W2, bf2, out);
}

// Round 8
// 1339.801 us; speedup vs baseline: 1.6072x; 1.1165x over previous
//
#include <hip/hip_runtime.h>

#define TT 2048
#define HH 64
#define II 6
#define OO 6
#define NTHR 512   // 8 waves = 2/SIMD pinned

typedef float    f32x4 __attribute__((ext_vector_type(4)));
typedef _Float16 f16x2 __attribute__((ext_vector_type(2)));
typedef _Float16 f16x8 __attribute__((ext_vector_type(8)));

__device__ __forceinline__ float fast_sig(float v) {
    return __builtin_amdgcn_rcpf(1.0f + __expf(-v));
}
__device__ __forceinline__ float fast_tanh(float v) {
    return 1.0f - 2.0f * __builtin_amdgcn_rcpf(__expf(2.0f * v) + 1.0f);
}
// quad_perm DPP cross-lane (VALU pipe, not LDS): xor1 = {1,0,3,2} -> 0xB1,
// xor2 = {2,3,0,1} -> 0x4E
__device__ __forceinline__ float dpp_xor1(float v) {
    return __int_as_float(__builtin_amdgcn_mov_dpp(
        __float_as_int(v), 0xB1, 0xF, 0xF, true));
}
__device__ __forceinline__ float dpp_xor2(float v) {
    return __int_as_float(__builtin_amdgcn_mov_dpp(
        __float_as_int(v), 0x4E, 0xF, 0xF, true));
}

__global__
__attribute__((amdgpu_flat_work_group_size(NTHR, NTHR)))
__attribute__((amdgpu_waves_per_eu(2, 2)))
void lstm_fused_kernel(const float* __restrict__ x,
                       const float* __restrict__ Wih0, const float* __restrict__ Whh0,
                       const float* __restrict__ b0,
                       const float* __restrict__ Wih1, const float* __restrict__ Whh1,
                       const float* __restrict__ b1,
                       const float* __restrict__ W1, const float* __restrict__ bf1,
                       const float* __restrict__ W2, const float* __restrict__ bf2,
                       float* __restrict__ out)
{
    const int row = blockIdx.x;        // batch row
    const int tid = threadIdx.x;
    const bool isA = tid < 256;        // A: layer0 gates + xg1 ; B: layer1 gates + FC
    const int fj = tid & 255;
    const int k  = fj >> 2;            // hidden unit (quad index)
    const int g  = fj & 3;             // lane-in-quad: owns cols [16g,16g+16)

    __shared__ __attribute__((aligned(16))) _Float16 h0f16[2][HH];
    __shared__ __attribute__((aligned(16))) _Float16 h1f16[2][HH];
    __shared__ __attribute__((aligned(16))) _Float16 rb16[2][HH];
    __shared__ __attribute__((aligned(16))) float    xgbuf[2][256];

    if (tid < HH) {
        h0f16[0][tid] = (_Float16)0.f; h0f16[1][tid] = (_Float16)0.f;
        h1f16[0][tid] = (_Float16)0.f; h1f16[1][tid] = (_Float16)0.f;
        rb16[0][tid]  = (_Float16)0.f; rb16[1][tid]  = (_Float16)0.f;
    }

    // per-lane weight slices: 16 cols [16g,16g+16) of 4 rows, packed f16x2.
    // A: wG = Whh0 rows {r*64+k}, wF = Wih1 rows {r*64+k}
    // B: wG = Whh1 rows {r*64+k}, wF[0..7] = W1 row k, wF[8..15] = W2 row k (k<6)
    f16x2 wG[32], wF[32];
    auto loadq = [&](const float* rowbase, f16x2* dst) {
        const f32x4* p4 = reinterpret_cast<const f32x4*>(rowbase + 16 * g);
        #pragma unroll
        for (int u = 0; u < 4; ++u) {
            f32x4 v = p4[u];
            dst[2*u]   = f16x2{(_Float16)v[0], (_Float16)v[1]};
            dst[2*u+1] = f16x2{(_Float16)v[2], (_Float16)v[3]};
        }
    };
    float biasF = 0.f;
    if (isA) {
        #pragma unroll
        for (int r = 0; r < 4; ++r) {
            loadq(Whh0 + (r*HH + k) * HH, &wG[8*r]);
            loadq(Wih1 + (r*HH + k) * HH, &wF[8*r]);
        }
        biasF = b1[g*HH + k];
    } else {
        #pragma unroll
        for (int r = 0; r < 4; ++r) loadq(Whh1 + (r*HH + k) * HH, &wG[8*r]);
        loadq(W1 + k * HH, &wF[0]);
        loadq(W2 + (k < OO ? k : 0) * HH, &wF[8]);
        loadq(W1 + k * HH, &wF[16]);   // dummy fill (kept for uniform ties)
        loadq(W1 + k * HH, &wF[24]);
        biasF = (g == 0) ? bf1[k] : ((g == 1 && k < OO) ? bf2[k] : 0.f);
    }
    // opaque ties: asm outputs can't be rematerialized as loads
    asm volatile("" : "+v"(wG[0]), "+v"(wG[1]), "+v"(wG[2]),  "+v"(wG[3]),
                      "+v"(wG[4]), "+v"(wG[5]), "+v"(wG[6]),  "+v"(wG[7]),
                      "+v"(wG[8]), "+v"(wG[9]), "+v"(wG[10]), "+v"(wG[11]),
                      "+v"(wG[12]),"+v"(wG[13]),"+v"(wG[14]), "+v"(wG[15]));
    asm volatile("" : "+v"(wG[16]),"+v"(wG[17]),"+v"(wG[18]), "+v"(wG[19]),
                      "+v"(wG[20]),"+v"(wG[21]),"+v"(wG[22]), "+v"(wG[23]),
                      "+v"(wG[24]),"+v"(wG[25]),"+v"(wG[26]), "+v"(wG[27]),
                      "+v"(wG[28]),"+v"(wG[29]),"+v"(wG[30]), "+v"(wG[31]));
    asm volatile("" : "+v"(wF[0]), "+v"(wF[1]), "+v"(wF[2]),  "+v"(wF[3]),
                      "+v"(wF[4]), "+v"(wF[5]), "+v"(wF[6]),  "+v"(wF[7]),
                      "+v"(wF[8]), "+v"(wF[9]), "+v"(wF[10]), "+v"(wF[11]),
                      "+v"(wF[12]),"+v"(wF[13]),"+v"(wF[14]), "+v"(wF[15]));
    asm volatile("" : "+v"(wF[16]),"+v"(wF[17]),"+v"(wF[18]), "+v"(wF[19]),
                      "+v"(wF[20]),"+v"(wF[21]),"+v"(wF[22]), "+v"(wF[23]),
                      "+v"(wF[24]),"+v"(wF[25]),"+v"(wF[26]), "+v"(wF[27]),
                      "+v"(wF[28]),"+v"(wF[29]),"+v"(wF[30]), "+v"(wF[31]));

    // A: full f32 x-row for own gate row j=g*64+k (x part is not quartered)
    float wx0=0.f,wx1=0.f,wx2=0.f,wx3=0.f,wx4=0.f,wx5=0.f, b0j=0.f;
    float xc0=0.f,xc1=0.f,xc2=0.f,xc3=0.f,xc4=0.f,xc5=0.f;
    const float* xrow = x + (size_t)row * TT * II;
    if (isA) {
        const int j = g * HH + k;
        wx0 = Wih0[j*II+0]; wx1 = Wih0[j*II+1]; wx2 = Wih0[j*II+2];
        wx3 = Wih0[j*II+3]; wx4 = Wih0[j*II+4]; wx5 = Wih0[j*II+5];
        b0j = b0[j];
        xc0 = xrow[0]; xc1 = xrow[1]; xc2 = xrow[2];
        xc3 = xrow[3]; xc4 = xrow[4]; xc5 = xrow[5];
    }

    float* outrow = out + (size_t)row * TT * OO;
    float c = 0.f;   // cell state, replicated across the 4 lanes of each quad

    __syncthreads();

    // slot parities (verified R6/R7): sl_prev=(t+1)&1 reads {h0[t-1],h1[t-3]} and
    // writes {xg1[t-1], rbuf s3}; sl_cur=t&1 writes {h0[t],h1[t-2]} and reads
    // {xgbuf s2, rbuf s4}
    for (int t = 0; t <= TT + 3; ++t) {
        const int sl_prev = (t + 1) & 1;
        const int sl_cur  = t & 1;

        if (isA) {
            const f16x8* hq = reinterpret_cast<const f16x8*>(&h0f16[sl_prev][16*g]);
            f16x8 ha = hq[0], hb = hq[1];           // own 16-element slice (32 B)
            float xg0p = b0j + wx0*xc0 + wx1*xc1 + wx2*xc2
                             + wx3*xc3 + wx4*xc4 + wx5*xc5;
            float pG0 = (g==0)? xg0p  : 0.f, pG1 = (g==1)? xg0p  : 0.f;
            float pG2 = (g==2)? xg0p  : 0.f, pG3 = (g==3)? xg0p  : 0.f;
            float pF0 = (g==0)? biasF : 0.f, pF1 = (g==1)? biasF : 0.f;
            float pF2 = (g==2)? biasF : 0.f, pF3 = (g==3)? biasF : 0.f;
            #pragma unroll
            for (int m = 0; m < 8; ++m) {
                f16x2 hm = (m < 4)
                    ? __builtin_shufflevector(ha, ha, 0, 1)
                    : __builtin_shufflevector(hb, hb, 0, 1);
                if (m == 1 || m == 5) hm = (m<4)?__builtin_shufflevector(ha,ha,2,3)
                                               :__builtin_shufflevector(hb,hb,2,3);
                if (m == 2 || m == 6) hm = (m<4)?__builtin_shufflevector(ha,ha,4,5)
                                               :__builtin_shufflevector(hb,hb,4,5);
                if (m == 3 || m == 7) hm = (m<4)?__builtin_shufflevector(ha,ha,6,7)
                                               :__builtin_shufflevector(hb,hb,6,7);
                pG0 = __builtin_amdgcn_fdot2(wG[m],    hm, pG0, false);
                pG1 = __builtin_amdgcn_fdot2(wG[8+m],  hm, pG1, false);
                pG2 = __builtin_amdgcn_fdot2(wG[16+m], hm, pG2, false);
                pG3 = __builtin_amdgcn_fdot2(wG[24+m], hm, pG3, false);
                pF0 = __builtin_amdgcn_fdot2(wF[m],    hm, pF0, false);
                pF1 = __builtin_amdgcn_fdot2(wF[8+m],  hm, pF1, false);
                pF2 = __builtin_amdgcn_fdot2(wF[16+m], hm, pF2, false);
                pF3 = __builtin_amdgcn_fdot2(wF[24+m], hm, pF3, false);
            }
            // quad tree-reduce: after 2 rounds ALL lanes hold ALL 4 totals
            pG0 += dpp_xor1(pG0); pG0 += dpp_xor2(pG0);
            pG1 += dpp_xor1(pG1); pG1 += dpp_xor2(pG1);
            pG2 += dpp_xor1(pG2); pG2 += dpp_xor2(pG2);
            pG3 += dpp_xor1(pG3); pG3 += dpp_xor2(pG3);
            pF0 += dpp_xor1(pF0); pF0 += dpp_xor2(pF0);
            pF1 += dpp_xor1(pF1); pF1 += dpp_xor2(pF1);
            pF2 += dpp_xor1(pF2); pF2 += dpp_xor2(pF2);
            pF3 += dpp_xor1(pF3); pF3 += dpp_xor2(pF3);
            if (t <= TT) {
                float tf = (g & 2) ? ((g & 1) ? pF3 : pF2)
                                   : ((g & 1) ? pF1 : pF0);
                xgbuf[sl_prev][fj] = tf;            // xg1[t-1] for row (fj&3)*64+(fj>>2)
            }
            if (t < TT) {
                float i_ = fast_sig(pG0), f_ = fast_sig(pG1);
                float gg = fast_tanh(pG2), o_ = fast_sig(pG3);
                c = f_ * c + i_ * gg;
                float h = o_ * fast_tanh(c);
                if (g == 0) h0f16[sl_cur][k] = (_Float16)h;
                if (t + 1 < TT) {
                    const float* xn = xrow + (size_t)(t + 1) * II;
                    xc0 = xn[0]; xc1 = xn[1]; xc2 = xn[2];
                    xc3 = xn[3]; xc4 = xn[4]; xc5 = xn[5];
                }
            }
        } else {
            const int s2 = t - 2, s3 = t - 3, s4 = t - 4;
            const f16x8* hq = reinterpret_cast<const f16x8*>(&h1f16[sl_prev][16*g]);
            const f16x8* rq = reinterpret_cast<const f16x8*>(&rb16[sl_cur][16*g]);
            f16x8 ha = hq[0], hb = hq[1];
            f16x8 ra = rq[0], rb = rq[1];
            float xgin = xgbuf[sl_cur][fj];         // b1 + Wih1.h0[s2], from A
            float pG0 = (g==0)? xgin  : 0.f, pG1 = (g==1)? xgin  : 0.f;
            float pG2 = (g==2)? xgin  : 0.f, pG3 = (g==3)? xgin  : 0.f;
            float pF0 = (g==0)? biasF : 0.f;        // W1 row k . h1 + bf1[k]
            float pF1 = (g==1)? biasF : 0.f;        // W2 row k . rbuf + bf2[k]
            #pragma unroll
            for (int m = 0; m < 8; ++m) {
                f16x2 hm, rm;
                switch (m) {
                  case 0: hm=__builtin_shufflevector(ha,ha,0,1); rm=__builtin_shufflevector(ra,ra,0,1); break;
                  case 1: hm=__builtin_shufflevector(ha,ha,2,3); rm=__builtin_shufflevector(ra,ra,2,3); break;
                  case 2: hm=__builtin_shufflevector(ha,ha,4,5); rm=__builtin_shufflevector(ra,ra,4,5); break;
                  case 3: hm=__builtin_shufflevector(ha,ha,6,7); rm=__builtin_shufflevector(ra,ra,6,7); break;
                  case 4: hm=__builtin_shufflevector(hb,hb,0,1); rm=__builtin_shufflevector(rb,rb,0,1); break;
                  case 5: hm=__builtin_shufflevector(hb,hb,2,3); rm=__builtin_shufflevector(rb,rb,2,3); break;
                  case 6: hm=__builtin_shufflevector(hb,hb,4,5); rm=__builtin_shufflevector(rb,rb,4,5); break;
                  default:hm=__builtin_shufflevector(hb,hb,6,7); rm=__builtin_shufflevector(rb,rb,6,7); break;
                }
                pG0 = __builtin_amdgcn_fdot2(wG[m],    hm, pG0, false);
                pG1 = __builtin_amdgcn_fdot2(wG[8+m],  hm, pG1, false);
                pG2 = __builtin_amdgcn_fdot2(wG[16+m], hm, pG2, false);
                pG3 = __builtin_amdgcn_fdot2(wG[24+m], hm, pG3, false);
                pF0 = __builtin_amdgcn_fdot2(wF[m],    hm, pF0, false);
                pF1 = __builtin_amdgcn_fdot2(wF[8+m],  rm, pF1, false);
            }
            pG0 += dpp_xor1(pG0); pG0 += dpp_xor2(pG0);
            pG1 += dpp_xor1(pG1); pG1 += dpp_xor2(pG1);
            pG2 += dpp_xor1(pG2); pG2 += dpp_xor2(pG2);
            pG3 += dpp_xor1(pG3); pG3 += dpp_xor2(pG3);
            pF0 += dpp_xor1(pF0); pF0 += dpp_xor2(pF0);
            pF1 += dpp_xor1(pF1); pF1 += dpp_xor2(pF1);
            if (s2 >= 0 && s2 < TT) {
                float i_ = fast_sig(pG0), f_ = fast_sig(pG1);
                float gg = fast_tanh(pG2), o_ = fast_sig(pG3);
                c = f_ * c + i_ * gg;
                float h = o_ * fast_tanh(c);
                if (g == 0) h1f16[sl_cur][k] = (_Float16)h;
            }
            if (s3 >= 0 && s3 < TT && g == 0)
                rb16[sl_prev][k] = (_Float16)fmaxf(pF0, 0.f);
            if (s4 >= 0 && s4 < TT && g == 1 && k < OO)
                outrow[(size_t)s4 * OO + k] = pF1;
        }
        __syncthreads();   // single barrier publishes all slot writes for iter t+1
    }
}

extern "C" void kernel_launch(void* const* d_in, const int* in_sizes, int n_in,
                              void* d_out, int out_size, void* d_ws, size_t ws_size,
                              hipStream_t stream) {
    const float* xp   = (const float*)d_in[0];
    const float* Wih0 = (const float*)d_in[1];
    const float* Whh0 = (const float*)d_in[2];
    const float* b0   = (const float*)d_in[3];
    const float* Wih1 = (const float*)d_in[4];
    const float* Whh1 = (const float*)d_in[5];
    const float* b1   = (const float*)d_in[6];
    const float* W1   = (const float*)d_in[7];
    const float* bf1  = (const float*)d_in[8];
    const float* W2   = (const float*)d_in[9];
    const float* bf2  = (const float*)d_in[10];
    float* out = (float*)d_out;

    lstm_fused_kernel<<<dim3(256), dim3(NTHR), 0, stream>>>(
        xp, Wih0, Whh0, b0, Wih1, Whh1, b1, W1, bf1, W2, bf2, out);
}

// Round 9
// 1276.897 us; speedup vs baseline: 1.6864x; 1.0493x over previous
//
#include <hip/hip_runtime.h>

#define TT 2048
#define HH 64
#define II 6
#define OO 6
#define NTHR 512   // 8 waves: 4 A-waves (layer0 + Wih1@h0), 4 B-waves (layer1 + FC)
#define HS 72      // f16 row stride for H0/H1/R LDS (16B-aligned, bank-spread)
#define XS 32      // Xb row stride (f16)
#define XGS 264    // XG1T slot stride (f32)

typedef float    f32x4 __attribute__((ext_vector_type(4)));
typedef _Float16 f16x8 __attribute__((ext_vector_type(8)));

__device__ __forceinline__ float fast_sig(float v) {
    return __builtin_amdgcn_rcpf(1.0f + __expf(-v));
}
__device__ __forceinline__ float fast_tanh(float v) {
    return 1.0f - 2.0f * __builtin_amdgcn_rcpf(__expf(2.0f * v) + 1.0f);
}

#define MFMA(a, b, c) __builtin_amdgcn_mfma_f32_16x16x32_f16((a), (b), (c), 0, 0, 0)

__global__
__attribute__((amdgpu_flat_work_group_size(NTHR, NTHR)))
__attribute__((amdgpu_waves_per_eu(2, 2)))
void lstm_mfma_kernel(const float* __restrict__ x,
                      const float* __restrict__ Wih0, const float* __restrict__ Whh0,
                      const float* __restrict__ b0,
                      const float* __restrict__ Wih1, const float* __restrict__ Whh1,
                      const float* __restrict__ b1,
                      const float* __restrict__ W1, const float* __restrict__ bf1,
                      const float* __restrict__ W2, const float* __restrict__ bf2,
                      float* __restrict__ out)
{
    const int row  = blockIdx.x;      // one batch row per block (M padded to 16)
    const int tid  = threadIdx.x;
    const int wid  = tid >> 6;        // wave id 0..7
    const int lane = tid & 63;
    const int n    = lane & 15;       // MFMA col-lane (A-row / B-col / D-col)
    const int q    = lane >> 4;       // k-group
    const bool isA = wid < 4;
    const int  w   = isA ? wid : wid - 4;   // role-local wave index 0..3

    // LDS: row 0 is the real batch row; rows 1-15 stay zero (M padding).
    __shared__ __attribute__((aligned(16))) _Float16 H0[2][16 * HS];
    __shared__ __attribute__((aligned(16))) _Float16 H1[2][16 * HS];
    __shared__ __attribute__((aligned(16))) _Float16 Rb[2][16 * HS];
    __shared__ __attribute__((aligned(16))) _Float16 Xb[2][16 * XS];  // [x(6)|0...]
    __shared__ __attribute__((aligned(16))) float    XG[2][XGS];      // xg1 strip (f32)

    for (int i = tid; i < 2 * 16 * HS; i += NTHR) {
        H0[0][i] = (_Float16)0.f;   // flat across both slots via [0][i] aliasing
    }
    // (H0 is [2][16*HS]; the loop above covered slot0+slot1 since i spans 2*16*HS)
    for (int i = tid; i < 2 * 16 * HS; i += NTHR) H1[0][i] = (_Float16)0.f;
    for (int i = tid; i < 2 * 16 * HS; i += NTHR) Rb[0][i] = (_Float16)0.f;
    for (int i = tid; i < 2 * 16 * XS; i += NTHR) Xb[0][i] = (_Float16)0.f;
    for (int i = tid; i < 2 * XGS;     i += NTHR) XG[0][i] = 0.f;

    // ---- build weight B-frags (once). Same k->elem map as the A-frag loads, so
    // any k-permutation cancels inside the MFMA dot. elem i <-> k = kbase+8q+i.
    f16x8 frag[20];
    float bias[8];
    #pragma unroll
    for (int i = 0; i < 8; ++i) bias[i] = 0.f;

    auto mk = [&](const float* W, int r, int ld, int kbase, int kmax, bool rok) {
        f16x8 f;
        #pragma unroll
        for (int i = 0; i < 8; ++i) {
            int kk = kbase + 8 * q + i;
            f[i] = (rok && kk < kmax) ? (_Float16)W[r * ld + kk] : (_Float16)0.f;
        }
        return f;
    };

    if (isA) {
        #pragma unroll
        for (int g = 0; g < 4; ++g) {
            const int r0 = g * HH + 16 * w + n;        // gate row (i,f,g,o stacked)
            frag[g * 3 + 0] = mk(Whh0, r0, HH, 0,  HH, true);
            frag[g * 3 + 1] = mk(Whh0, r0, HH, 32, HH, true);
            frag[g * 3 + 2] = mk(Wih0, r0, II, 0,  II, true);   // x-chunk
            bias[g] = b0[r0];
            const int r1 = 16 * (4 * g + w) + n;       // xg1 output index
            frag[12 + g * 2 + 0] = mk(Wih1, r1, HH, 0,  HH, true);
            frag[12 + g * 2 + 1] = mk(Wih1, r1, HH, 32, HH, true);
            bias[4 + g] = b1[r1];
        }
    } else {
        #pragma unroll
        for (int g = 0; g < 4; ++g) {
            const int r0 = g * HH + 16 * w + n;
            frag[g * 2 + 0] = mk(Whh1, r0, HH, 0,  HH, true);
            frag[g * 2 + 1] = mk(Whh1, r0, HH, 32, HH, true);
        }
        const int rf = 16 * w + n;
        frag[8]  = mk(W1, rf, HH, 0,  HH, true);
        frag[9]  = mk(W1, rf, HH, 32, HH, true);
        bias[0] = bf1[rf];
        frag[10] = mk(W2, n, HH, 0,  HH, n < OO);
        frag[11] = mk(W2, n, HH, 32, HH, n < OO);
        bias[1] = (n < OO) ? bf2[n] : 0.f;
        #pragma unroll
        for (int i = 12; i < 20; ++i) frag[i] = frag[0];   // unused
    }

    const float* xrow   = x   + (size_t)row * TT * II;
    float*       outrow = out + (size_t)row * TT * OO;

    // stage x[0]
    if (tid < II) Xb[0][tid] = (_Float16)xrow[tid];

    float cst = 0.f;   // cell state: A lanes 0-15 hold c0[unit 16w+n]; B: c1
    __syncthreads();

    // slot parity (verified R6-R8): slp=(t+1)&1 holds {h0[t-1], h1[t-3], r[t-3]w},
    // slc=t&1 holds {h0[t]w, h1[t-2]w, xg1[t-2]r, r[t-4]r, x[t]r}
    for (int t = 0; t <= TT + 3; ++t) {
        const int slp = (t + 1) & 1;
        const int slc = t & 1;

        if (isA) {
            const f16x8 a0 = *reinterpret_cast<const f16x8*>(&H0[slp][n * HS + 8 * q]);
            const f16x8 a1 = *reinterpret_cast<const f16x8*>(&H0[slp][n * HS + 32 + 8 * q]);
            const f16x8 a2 = *reinterpret_cast<const f16x8*>(&Xb[slc][n * XS + 8 * q]);
            f32x4 d0, d1, d2, d3;
            #pragma unroll
            for (int g = 0; g < 4; ++g) {
                f32x4 acc = {bias[g], bias[g], bias[g], bias[g]};
                acc = MFMA(a0, frag[g * 3 + 0], acc);
                acc = MFMA(a1, frag[g * 3 + 1], acc);
                acc = MFMA(a2, frag[g * 3 + 2], acc);
                if (g == 0) d0 = acc; else if (g == 1) d1 = acc;
                else if (g == 2) d2 = acc; else d3 = acc;
                // G1b: xg1 = b1 + Wih1 . h0[t-1]  (same a0,a1 operands)
                f32x4 ae = {bias[4 + g], bias[4 + g], bias[4 + g], bias[4 + g]};
                ae = MFMA(a0, frag[12 + g * 2 + 0], ae);
                ae = MFMA(a1, frag[12 + g * 2 + 1], ae);
                if (lane < 16) XG[slp][16 * (4 * g + w) + lane] = ae[0];
            }
            if (t < TT) {
                float i_ = fast_sig(d0[0]), f_ = fast_sig(d1[0]);
                float g_ = fast_tanh(d2[0]), o_ = fast_sig(d3[0]);
                cst = f_ * cst + i_ * g_;
                float h = o_ * fast_tanh(cst);
                if (lane < 16) H0[slc][16 * w + lane] = (_Float16)h;
            }
            if (wid == 0 && lane < II && t + 1 < TT)
                Xb[slp][lane] = (_Float16)xrow[(size_t)(t + 1) * II + lane];
        } else {
            const int s2 = t - 2, s3 = t - 3, s4 = t - 4;
            const f16x8 a0 = *reinterpret_cast<const f16x8*>(&H1[slp][n * HS + 8 * q]);
            const f16x8 a1 = *reinterpret_cast<const f16x8*>(&H1[slp][n * HS + 32 + 8 * q]);
            f32x4 d0, d1, d2, d3;
            #pragma unroll
            for (int g = 0; g < 4; ++g) {
                const float xg = XG[slc][16 * (4 * g + w) + n];  // b1+Wih1.h0[s2]
                f32x4 acc = {xg, xg, xg, xg};
                acc = MFMA(a0, frag[g * 2 + 0], acc);
                acc = MFMA(a1, frag[g * 2 + 1], acc);
                if (g == 0) d0 = acc; else if (g == 1) d1 = acc;
                else if (g == 2) d2 = acc; else d3 = acc;
            }
            if (s2 >= 0 && s2 < TT) {
                float i_ = fast_sig(d0[0]), f_ = fast_sig(d1[0]);
                float g_ = fast_tanh(d2[0]), o_ = fast_sig(d3[0]);
                cst = f_ * cst + i_ * g_;
                float h = o_ * fast_tanh(cst);
                if (lane < 16) H1[slc][16 * w + lane] = (_Float16)h;
            }
            {   // FC1: relu(W1 . h1[s3] + bf1) -> Rb  (reuses a0,a1)
                f32x4 acc = {bias[0], bias[0], bias[0], bias[0]};
                acc = MFMA(a0, frag[8], acc);
                acc = MFMA(a1, frag[9], acc);
                if (s3 >= 0 && s3 < TT && lane < 16)
                    Rb[slp][16 * w + lane] = (_Float16)fmaxf(acc[0], 0.f);
            }
            if (w == 0) {   // FC2: W2 . r[s4] + bf2 -> out
                const f16x8 r0 = *reinterpret_cast<const f16x8*>(&Rb[slc][n * HS + 8 * q]);
                const f16x8 r1 = *reinterpret_cast<const f16x8*>(&Rb[slc][n * HS + 32 + 8 * q]);
                f32x4 acc = {bias[1], bias[1], bias[1], bias[1]};
                acc = MFMA(r0, frag[10], acc);
                acc = MFMA(r1, frag[11], acc);
                if (s4 >= 0 && s4 < TT && lane < OO)
                    outrow[(size_t)s4 * OO + lane] = acc[0];
            }
        }
        __syncthreads();   // single barrier publishes all slot writes for iter t+1
    }
}

extern "C" void kernel_launch(void* const* d_in, const int* in_sizes, int n_in,
                              void* d_out, int out_size, void* d_ws, size_t ws_size,
                              hipStream_t stream) {
    const float* xp   = (const float*)d_in[0];
    const float* Wih0 = (const float*)d_in[1];
    const float* Whh0 = (const float*)d_in[2];
    const float* b0   = (const float*)d_in[3];
    const float* Wih1 = (const float*)d_in[4];
    const float* Whh1 = (const float*)d_in[5];
    const float* b1   = (const float*)d_in[6];
    const float* W1   = (const float*)d_in[7];
    const float* bf1  = (const float*)d_in[8];
    const float* W2   = (const float*)d_in[9];
    const float* bf2  = (const float*)d_in[10];
    float* outp = (float*)d_out;

    lstm_mfma_kernel<<<dim3(256), dim3(NTHR), 0, stream>>>(
        xp, Wih0, Whh0, b0, Wih1, Whh1, b1, W1, bf1, W2, bf2, outp);
}

// Round 10
// 1214.914 us; speedup vs baseline: 1.7725x; 1.0510x over previous
//
#include <hip/hip_runtime.h>

#define TT 2048
#define HH 64
#define II 6
#define OO 6
#define NTHR 512   // 8 waves: 4 A-waves (layer0 + Wih1@h0), 4 B-waves (layer1 + FC)

typedef float    f32x4 __attribute__((ext_vector_type(4)));
typedef _Float16 f16x8 __attribute__((ext_vector_type(8)));

__device__ __forceinline__ float fast_sig(float v) {
    return __builtin_amdgcn_rcpf(1.0f + __expf(-v));
}
__device__ __forceinline__ float fast_tanh(float v) {
    return 1.0f - 2.0f * __builtin_amdgcn_rcpf(__expf(2.0f * v) + 1.0f);
}

#define MFMA(a, b, c) __builtin_amdgcn_mfma_f32_16x16x32_f16((a), (b), (c), 0, 0, 0)

__global__
__attribute__((amdgpu_flat_work_group_size(NTHR, NTHR)))
__attribute__((amdgpu_waves_per_eu(2, 2)))
void lstm_mfma_kernel(const float* __restrict__ x,
                      const float* __restrict__ Wih0, const float* __restrict__ Whh0,
                      const float* __restrict__ b0,
                      const float* __restrict__ Wih1, const float* __restrict__ Whh1,
                      const float* __restrict__ b1,
                      const float* __restrict__ W1, const float* __restrict__ bf1,
                      const float* __restrict__ W2, const float* __restrict__ bf2,
                      float* __restrict__ out)
{
    const int row  = blockIdx.x;      // one batch row per block
    const int tid  = threadIdx.x;
    const int wid  = tid >> 6;        // wave id 0..7
    const int lane = tid & 63;
    const int n    = lane & 15;       // MFMA col-lane (B-col / D-col)
    const int q    = lane >> 4;       // k-group: lane holds k = 8q..8q+7 (+32 for a1)
    const bool isA = wid < 4;
    const int  w   = isA ? wid : wid - 4;   // role-local wave index 0..3

    // Only the REAL row (D/A row 0) is stored; all 16 A-rows get identical data
    // (broadcast). Garbage rows 1-15 of D are discarded, so no zero-padding tile.
    __shared__ __attribute__((aligned(16))) _Float16 H0[2][HH];
    __shared__ __attribute__((aligned(16))) _Float16 H1[2][HH];
    __shared__ __attribute__((aligned(16))) _Float16 Rb[2][HH];
    __shared__ __attribute__((aligned(16))) _Float16 Xb[2][32];  // x | ZERO pad (k<32)
    __shared__ __attribute__((aligned(16))) float    XG[2][256]; // xg1 strip (f32)

    if (tid < HH) {
        H0[0][tid] = (_Float16)0.f; H0[1][tid] = (_Float16)0.f;
        H1[0][tid] = (_Float16)0.f; H1[1][tid] = (_Float16)0.f;
        Rb[0][tid] = (_Float16)0.f; Rb[1][tid] = (_Float16)0.f;
    }
    if (tid < 32) { Xb[0][tid] = (_Float16)0.f; Xb[1][tid] = (_Float16)0.f; }
    if (tid < 256) { XG[0][tid] = 0.f; XG[1][tid] = 0.f; }

    // ---- build weight B-frags (once). Same k->elem map as the A-frag reads
    // (elem i <-> k = kbase + 8q + i), so the mapping cancels inside the dot.
    f16x8 frag[20];
    float bias[8];
    #pragma unroll
    for (int i = 0; i < 8; ++i) bias[i] = 0.f;

    auto mk = [&](const float* W, int r, int ld, int kbase, int kmax, bool rok) {
        f16x8 f;
        #pragma unroll
        for (int i = 0; i < 8; ++i) {
            int kk = kbase + 8 * q + i;
            f[i] = (rok && kk < kmax) ? (_Float16)W[r * ld + kk] : (_Float16)0.f;
        }
        return f;
    };

    if (isA) {
        #pragma unroll
        for (int g = 0; g < 4; ++g) {
            const int r0 = g * HH + 16 * w + n;        // gate row (i,f,g,o stacked)
            frag[g * 3 + 0] = mk(Whh0, r0, HH, 0,  HH, true);
            frag[g * 3 + 1] = mk(Whh0, r0, HH, 32, HH, true);
            frag[g * 3 + 2] = mk(Wih0, r0, II, 0,  II, true);   // x-chunk (k>=6 zero)
            bias[g] = b0[r0];
            const int r1 = 16 * (4 * g + w) + n;       // xg1 output index
            frag[12 + g * 2 + 0] = mk(Wih1, r1, HH, 0,  HH, true);
            frag[12 + g * 2 + 1] = mk(Wih1, r1, HH, 32, HH, true);
            bias[4 + g] = b1[r1];
        }
    } else {
        #pragma unroll
        for (int g = 0; g < 4; ++g) {
            const int r0 = g * HH + 16 * w + n;
            frag[g * 2 + 0] = mk(Whh1, r0, HH, 0,  HH, true);
            frag[g * 2 + 1] = mk(Whh1, r0, HH, 32, HH, true);
        }
        const int rf = 16 * w + n;
        frag[8]  = mk(W1, rf, HH, 0,  HH, true);
        frag[9]  = mk(W1, rf, HH, 32, HH, true);
        bias[0] = bf1[rf];
        frag[10] = mk(W2, n, HH, 0,  HH, n < OO);
        frag[11] = mk(W2, n, HH, 32, HH, n < OO);
        bias[1] = (n < OO) ? bf2[n] : 0.f;
        #pragma unroll
        for (int i = 12; i < 20; ++i) frag[i] = frag[0];   // unused
    }

    const float* xrow   = x   + (size_t)row * TT * II;
    float*       outrow = out + (size_t)row * TT * OO;

    // stage x[0]
    if (tid < II) Xb[0][tid] = (_Float16)xrow[tid];

    float cst = 0.f;   // cell state: A lanes 0-15 hold c0[unit 16w+n]; B: c1
    __syncthreads();

    // slot parity (verified R6-R9): slp=(t+1)&1 holds {h0[t-1], h1[t-3], r[t-3]w},
    // slc=t&1 holds {h0[t]w, h1[t-2]w, xg1[t-2]r, r[t-4]r, x[t]r}
    for (int t = 0; t <= TT + 3; ++t) {
        const int slp = (t + 1) & 1;
        const int slc = t & 1;

        if (isA) {
            // broadcast A-frags: every n-lane in a q-group reads the SAME 16B
            const f16x8 a0 = *reinterpret_cast<const f16x8*>(&H0[slp][8 * q]);
            const f16x8 a1 = *reinterpret_cast<const f16x8*>(&H0[slp][32 + 8 * q]);
            const f16x8 a2 = *reinterpret_cast<const f16x8*>(&Xb[slc][8 * q]);
            f32x4 d0, d1, d2, d3;
            #pragma unroll
            for (int g = 0; g < 4; ++g) {
                f32x4 acc = {bias[g], bias[g], bias[g], bias[g]};
                acc = MFMA(a0, frag[g * 3 + 0], acc);
                acc = MFMA(a1, frag[g * 3 + 1], acc);
                acc = MFMA(a2, frag[g * 3 + 2], acc);
                if (g == 0) d0 = acc; else if (g == 1) d1 = acc;
                else if (g == 2) d2 = acc; else d3 = acc;
                // G1b: xg1 = b1 + Wih1 . h0[t-1]  (same a0,a1 operands)
                f32x4 ae = {bias[4 + g], bias[4 + g], bias[4 + g], bias[4 + g]};
                ae = MFMA(a0, frag[12 + g * 2 + 0], ae);
                ae = MFMA(a1, frag[12 + g * 2 + 1], ae);
                if (lane < 16) XG[slp][16 * (4 * g + w) + lane] = ae[0];
            }
            if (t < TT) {
                float i_ = fast_sig(d0[0]), f_ = fast_sig(d1[0]);
                float g_ = fast_tanh(d2[0]), o_ = fast_sig(d3[0]);
                cst = f_ * cst + i_ * g_;
                float h = o_ * fast_tanh(cst);
                if (lane < 16) H0[slc][16 * w + lane] = (_Float16)h;
            }
            if (wid == 0 && lane < II && t + 1 < TT)
                Xb[slp][lane] = (_Float16)xrow[(size_t)(t + 1) * II + lane];
        } else {
            const int s2 = t - 2, s3 = t - 3, s4 = t - 4;
            const f16x8 a0 = *reinterpret_cast<const f16x8*>(&H1[slp][8 * q]);
            const f16x8 a1 = *reinterpret_cast<const f16x8*>(&H1[slp][32 + 8 * q]);
            f32x4 d0, d1, d2, d3;
            #pragma unroll
            for (int g = 0; g < 4; ++g) {
                const float xg = XG[slc][16 * (4 * g + w) + n];  // b1+Wih1.h0[s2]
                f32x4 acc = {xg, xg, xg, xg};
                acc = MFMA(a0, frag[g * 2 + 0], acc);
                acc = MFMA(a1, frag[g * 2 + 1], acc);
                if (g == 0) d0 = acc; else if (g == 1) d1 = acc;
                else if (g == 2) d2 = acc; else d3 = acc;
            }
            if (s2 >= 0 && s2 < TT) {
                float i_ = fast_sig(d0[0]), f_ = fast_sig(d1[0]);
                float g_ = fast_tanh(d2[0]), o_ = fast_sig(d3[0]);
                cst = f_ * cst + i_ * g_;
                float h = o_ * fast_tanh(cst);
                if (lane < 16) H1[slc][16 * w + lane] = (_Float16)h;
            }
            {   // FC1: relu(W1 . h1[s3] + bf1) -> Rb  (reuses a0,a1)
                f32x4 acc = {bias[0], bias[0], bias[0], bias[0]};
                acc = MFMA(a0, frag[8], acc);
                acc = MFMA(a1, frag[9], acc);
                if (s3 >= 0 && s3 < TT && lane < 16)
                    Rb[slp][16 * w + lane] = (_Float16)fmaxf(acc[0], 0.f);
            }
            if (w == 0) {   // FC2: W2 . r[s4] + bf2 -> out
                const f16x8 r0 = *reinterpret_cast<const f16x8*>(&Rb[slc][8 * q]);
                const f16x8 r1 = *reinterpret_cast<const f16x8*>(&Rb[slc][32 + 8 * q]);
                f32x4 acc = {bias[1], bias[1], bias[1], bias[1]};
                acc = MFMA(r0, frag[10], acc);
                acc = MFMA(r1, frag[11], acc);
                if (s4 >= 0 && s4 < TT && lane < OO)
                    outrow[(size_t)s4 * OO + lane] = acc[0];
            }
        }
        __syncthreads();   // single barrier publishes all slot writes for iter t+1
    }
}

extern "C" void kernel_launch(void* const* d_in, const int* in_sizes, int n_in,
                              void* d_out, int out_size, void* d_ws, size_t ws_size,
                              hipStream_t stream) {
    const float* xp   = (const float*)d_in[0];
    const float* Wih0 = (const float*)d_in[1];
    const float* Whh0 = (const float*)d_in[2];
    const float* b0   = (const float*)d_in[3];
    const float* Wih1 = (const float*)d_in[4];
    const float* Whh1 = (const float*)d_in[5];
    const float* b1   = (const float*)d_in[6];
    const float* W1   = (const float*)d_in[7];
    const float* bf1  = (const float*)d_in[8];
    const float* W2   = (const float*)d_in[9];
    const float* bf2  = (const float*)d_in[10];
    float* outp = (float*)d_out;

    lstm_mfma_kernel<<<dim3(256), dim3(NTHR), 0, stream>>>(
        xp, Wih0, Whh0, b0, Wih1, Whh1, b1, W1, bf1, W2, bf2, outp);
}